// Round 1
// baseline (1087.370 us; speedup 1.0000x reference)
//
#include <hip/hip_runtime.h>

// CNF forward: 8 fixed dopri5 steps, 6 stages each, rows independent.
// One persistent kernel: 256 blocks x 512 threads; wave handles 16 rows.
// MFMA 16x16x32 bf16; weights in LDS; k's/state/ghv in registers (C-layout).

typedef __bf16 bf16x8 __attribute__((ext_vector_type(8)));
typedef float  f32x4  __attribute__((ext_vector_type(4)));

#define MFMA16(a, b, c) __builtin_amdgcn_mfma_f32_16x16x32_bf16((a), (b), (c), 0, 0, 0)

__device__ __forceinline__ unsigned int bfbits(float x) {
    __bf16 b = (__bf16)x;                      // RNE fp32->bf16
    return (unsigned int)__builtin_bit_cast(unsigned short, b);
}
__device__ __forceinline__ float frombits(unsigned int u16) {
    return __builtin_bit_cast(float, u16 << 16);
}
__device__ __forceinline__ unsigned int pack2(float lo, float hi) {
    return bfbits(lo) | (bfbits(hi) << 16);
}
__device__ __forceinline__ float fast_tanh(float x) {
    // tanh(x) = 1 - 2/(exp(2x)+1); exp overflow/underflow saturate correctly.
    float e = __expf(2.0f * x);
    return 1.0f - 2.0f * __builtin_amdgcn_rcpf(e + 1.0f);
}

extern "C" __global__ void __launch_bounds__(512, 2)
cnf_kernel(const float* __restrict__ Yg, const float* __restrict__ Eg,
           const float* __restrict__ W1g, const float* __restrict__ b1g,
           const float* __restrict__ W2g, const float* __restrict__ b2g,
           float* __restrict__ Og)
{
    // ---- LDS (113.5 KB; gfx950 WG group segment is 160 KiB) ----
    __shared__ __align__(16) __bf16 sW1aT[256 * 72];   // [j][d] W1a^T, d-contig per j
    __shared__ __align__(16) __bf16 sW2U[256 * 72];    // phase1: W2 [j][d]; phase2: W2^T [d*264+j]
    __shared__ __align__(16) __bf16 sY[8][16 * 72];    // per-wave y stage buf [m][d]
    __shared__ __align__(16) __bf16 sH[8][16 * 40];    // per-wave h chunk [m][kloc 0..31]
    __shared__ __align__(16) float  sScr[8][16 * 17 + 4]; // per-wave transpose scratch
    __shared__ float sB1[256], sW1t[256], sB2[64];

    const int tid  = threadIdx.x;
    const int wave = tid >> 6;
    const int lane = tid & 63;
    const int quad = lane >> 4;
    const int l16  = lane & 15;
    const int row0 = blockIdx.x * 128 + wave * 16;  // 16 rows per wave
    const int rr   = quad * 4;                      // C-layout row base (rows rr..rr+3)

    // ---------------- phase-1 weight staging ----------------
    for (int idx = tid; idx < 64 * 256; idx += 512) {         // W1a^T
        int d = idx >> 8, j = idx & 255;
        sW1aT[j * 72 + d] = (__bf16)W1g[idx];
    }
    for (int idx = tid; idx < 256 * 64; idx += 512) {         // W2 row-major
        int j = idx >> 6, d = idx & 63;
        sW2U[j * 72 + d] = (__bf16)W2g[idx];
    }
    for (int j = tid; j < 256; j += 512) { sB1[j] = b1g[j]; sW1t[j] = W1g[64 * 256 + j]; }
    if (tid < 64) sB2[tid] = b2g[tid];
    __syncthreads();

    __bf16* yb  = sY[wave];
    __bf16* hb  = sH[wave];
    float*  scr = sScr[wave];

    // ---------------- stage e into ybuf (wave-local) ----------------
    #pragma unroll
    for (int nt = 0; nt < 4; ++nt)
        #pragma unroll
        for (int rg = 0; rg < 4; ++rg)
            yb[(rr + rg) * 72 + nt * 16 + l16] =
                (__bf16)Eg[(row0 + rr + rg) * 64 + nt * 16 + l16];

    // A-frags of e: A[m=l16][k=d], d-contig
    bf16x8 ae0 = *(const bf16x8*)(yb + l16 * 72 + quad * 8);
    bf16x8 ae1 = *(const bf16x8*)(yb + l16 * 72 + 32 + quad * 8);

    // ---------------- precompute ghv = (e@W1a) * (e@W2^T), C-layout regs ----------------
    unsigned int ghvp[32];  // [jt][pair], bf16x2
    #pragma unroll
    for (int tt = 0; tt < 16; ++tt) {
        f32x4 vacc = {0.f, 0.f, 0.f, 0.f};
        f32x4 gacc = {0.f, 0.f, 0.f, 0.f};
        // v tile: A=e, B=W1a (k=d contig via sW1aT)
        bf16x8 wb0 = *(const bf16x8*)(sW1aT + (tt * 16 + l16) * 72 + quad * 8);
        bf16x8 wb1 = *(const bf16x8*)(sW1aT + (tt * 16 + l16) * 72 + 32 + quad * 8);
        vacc = MFMA16(ae0, wb0, vacc);
        vacc = MFMA16(ae1, wb1, vacc);
        // gh0^T tile: A=W2 rows j (k=d contig), B=e^T (same frags as ae)
        bf16x8 aw0 = *(const bf16x8*)(sW2U + (tt * 16 + l16) * 72 + quad * 8);
        bf16x8 aw1 = *(const bf16x8*)(sW2U + (tt * 16 + l16) * 72 + 32 + quad * 8);
        gacc = MFMA16(aw0, ae0, gacc);
        gacc = MFMA16(aw1, ae1, gacc);
        // gacc lane holds gh0[j_local=rr+rg][r_hat=l16]; transpose via scratch
        #pragma unroll
        for (int rg = 0; rg < 4; ++rg) scr[(rr + rg) * 17 + l16] = gacc[rg];
        __syncthreads();
        float p0 = scr[l16 * 17 + rr + 0] * vacc[0];
        float p1 = scr[l16 * 17 + rr + 1] * vacc[1];
        float p2 = scr[l16 * 17 + rr + 2] * vacc[2];
        float p3 = scr[l16 * 17 + rr + 3] * vacc[3];
        ghvp[tt * 2 + 0] = pack2(p0, p1);
        ghvp[tt * 2 + 1] = pack2(p2, p3);
        __syncthreads();
    }

    // ---------------- load z state (fp32, C-layout regs) ----------------
    float z[4][4];  // [nt][reg]: (row=rr+reg, d=nt*16+l16)
    #pragma unroll
    for (int nt = 0; nt < 4; ++nt)
        #pragma unroll
        for (int rg = 0; rg < 4; ++rg)
            z[nt][rg] = Yg[(row0 + rr + rg) * 64 + nt * 16 + l16];

    // ---------------- phase-2: overwrite union region with W2^T ----------------
    __syncthreads();
    for (int idx = tid; idx < 256 * 64; idx += 512) {
        int j = idx >> 6, d = idx & 63;
        sW2U[d * 264 + j] = (__bf16)W2g[idx];  // [d][j], j-contig per d
    }
    __syncthreads();

    // ---------------- dopri5 main loop (no block syncs inside) ----------------
    constexpr float AT[6][5] = {
        {0.f, 0.f, 0.f, 0.f, 0.f},
        {0.2f, 0.f, 0.f, 0.f, 0.f},
        {3.f / 40.f, 9.f / 40.f, 0.f, 0.f, 0.f},
        {44.f / 45.f, -56.f / 15.f, 32.f / 9.f, 0.f, 0.f},
        {19372.f / 6561.f, -25360.f / 2187.f, 64448.f / 6561.f, -212.f / 729.f, 0.f},
        {9017.f / 3168.f, -355.f / 33.f, 46732.f / 5247.f, 49.f / 176.f, -5103.f / 18656.f},
    };
    constexpr float CTv[6] = {0.f, 0.2f, 0.3f, 0.8f, 8.f / 9.f, 1.f};
    constexpr float BTv[6] = {35.f / 384.f, 0.f, 500.f / 1113.f, 125.f / 192.f,
                              -2187.f / 6784.f, 11.f / 84.f};
    const float dt = 0.125f;

    unsigned int kp[6][8];   // k_dz bf16-packed, [stage][nt*2+pair]
    float klp[6][4];         // +div per stage (k_lp = -div)
    float lp[4] = {0.f, 0.f, 0.f, 0.f};

    for (int step = 0; step < 8; ++step) {
        const float t0 = dt * (float)step;
        #pragma unroll
        for (int st = 0; st < 6; ++st) {
            // ---- build stage state y = z + dt*sum(a_ij k_j) -> ybuf (bf16) ----
            #pragma unroll
            for (int nt = 0; nt < 4; ++nt) {
                #pragma unroll
                for (int pr = 0; pr < 2; ++pr) {
                    float a0 = 0.f, a1 = 0.f;
                    #pragma unroll
                    for (int jj = 0; jj < 5; ++jj) {
                        if (jj < st) {
                            const float aco = AT[st][jj];
                            unsigned int p = kp[jj][nt * 2 + pr];
                            a0 += aco * frombits(p & 0xffffu);
                            a1 += aco * frombits(p >> 16);
                        }
                    }
                    float y0 = z[nt][pr * 2 + 0] + dt * a0;
                    float y1 = z[nt][pr * 2 + 1] + dt * a1;
                    yb[(rr + pr * 2 + 0) * 72 + nt * 16 + l16] = (__bf16)y0;
                    yb[(rr + pr * 2 + 1) * 72 + nt * 16 + l16] = (__bf16)y1;
                }
            }
            const float ti = t0 + CTv[st] * dt;

            // ---- RHS eval ----
            bf16x8 a10 = *(const bf16x8*)(yb + l16 * 72 + quad * 8);
            bf16x8 a11 = *(const bf16x8*)(yb + l16 * 72 + 32 + quad * 8);
            f32x4 fa0 = {0.f, 0.f, 0.f, 0.f}, fa1 = {0.f, 0.f, 0.f, 0.f};
            f32x4 fa2 = {0.f, 0.f, 0.f, 0.f}, fa3 = {0.f, 0.f, 0.f, 0.f};
            float dv0 = 0.f, dv1 = 0.f, dv2 = 0.f, dv3 = 0.f;
            #pragma unroll
            for (int kk2 = 0; kk2 < 8; ++kk2) {
                #pragma unroll
                for (int hf = 0; hf < 2; ++hf) {
                    const int jt = kk2 * 2 + hf;
                    f32x4 ua = {0.f, 0.f, 0.f, 0.f};
                    bf16x8 wb0 = *(const bf16x8*)(sW1aT + (jt * 16 + l16) * 72 + quad * 8);
                    ua = MFMA16(a10, wb0, ua);
                    bf16x8 wb1 = *(const bf16x8*)(sW1aT + (jt * 16 + l16) * 72 + 32 + quad * 8);
                    ua = MFMA16(a11, wb1, ua);
                    const int j = jt * 16 + l16;
                    const float bw = sB1[j] + ti * sW1t[j];
                    float h0 = fast_tanh(ua[0] + bw);
                    float h1 = fast_tanh(ua[1] + bw);
                    float h2 = fast_tanh(ua[2] + bw);
                    float h3 = fast_tanh(ua[3] + bw);
                    unsigned int gp0 = ghvp[jt * 2 + 0], gp1 = ghvp[jt * 2 + 1];
                    dv0 += frombits(gp0 & 0xffffu) * (1.f - h0 * h0);
                    dv1 += frombits(gp0 >> 16)     * (1.f - h1 * h1);
                    dv2 += frombits(gp1 & 0xffffu) * (1.f - h2 * h2);
                    dv3 += frombits(gp1 >> 16)     * (1.f - h3 * h3);
                    __bf16* hw = hb + hf * 16 + l16;
                    hw[(rr + 0) * 40] = (__bf16)h0;
                    hw[(rr + 1) * 40] = (__bf16)h1;
                    hw[(rr + 2) * 40] = (__bf16)h2;
                    hw[(rr + 3) * 40] = (__bf16)h3;
                }
                // matmul-2 K-chunk: f += h_chunk @ W2[kk2*32:+32, :]
                bf16x8 a2  = *(const bf16x8*)(hb + l16 * 40 + quad * 8);
                bf16x8 w20 = *(const bf16x8*)(sW2U + ( 0 + l16) * 264 + kk2 * 32 + quad * 8);
                fa0 = MFMA16(a2, w20, fa0);
                bf16x8 w21 = *(const bf16x8*)(sW2U + (16 + l16) * 264 + kk2 * 32 + quad * 8);
                fa1 = MFMA16(a2, w21, fa1);
                bf16x8 w22 = *(const bf16x8*)(sW2U + (32 + l16) * 264 + kk2 * 32 + quad * 8);
                fa2 = MFMA16(a2, w22, fa2);
                bf16x8 w23 = *(const bf16x8*)(sW2U + (48 + l16) * 264 + kk2 * 32 + quad * 8);
                fa3 = MFMA16(a2, w23, fa3);
            }
            // epilogue: + b2, pack k_dz
            {
                float bb0 = sB2[ 0 + l16], bb1 = sB2[16 + l16];
                float bb2 = sB2[32 + l16], bb3 = sB2[48 + l16];
                kp[st][0] = pack2(fa0[0] + bb0, fa0[1] + bb0);
                kp[st][1] = pack2(fa0[2] + bb0, fa0[3] + bb0);
                kp[st][2] = pack2(fa1[0] + bb1, fa1[1] + bb1);
                kp[st][3] = pack2(fa1[2] + bb1, fa1[3] + bb1);
                kp[st][4] = pack2(fa2[0] + bb2, fa2[1] + bb2);
                kp[st][5] = pack2(fa2[2] + bb2, fa2[3] + bb2);
                kp[st][6] = pack2(fa3[0] + bb3, fa3[1] + bb3);
                kp[st][7] = pack2(fa3[2] + bb3, fa3[3] + bb3);
            }
            // div reduction across the 16 j-lanes (same quad = same rows)
            dv0 += __shfl_xor(dv0, 1); dv0 += __shfl_xor(dv0, 2);
            dv0 += __shfl_xor(dv0, 4); dv0 += __shfl_xor(dv0, 8);
            dv1 += __shfl_xor(dv1, 1); dv1 += __shfl_xor(dv1, 2);
            dv1 += __shfl_xor(dv1, 4); dv1 += __shfl_xor(dv1, 8);
            dv2 += __shfl_xor(dv2, 1); dv2 += __shfl_xor(dv2, 2);
            dv2 += __shfl_xor(dv2, 4); dv2 += __shfl_xor(dv2, 8);
            dv3 += __shfl_xor(dv3, 1); dv3 += __shfl_xor(dv3, 2);
            dv3 += __shfl_xor(dv3, 4); dv3 += __shfl_xor(dv3, 8);
            klp[st][0] = dv0; klp[st][1] = dv1; klp[st][2] = dv2; klp[st][3] = dv3;
        }

        // ---- combine: z += dt*sum(b_i k_i); lp += dt*sum(b_i * (-div_i)) ----
        #pragma unroll
        for (int nt = 0; nt < 4; ++nt) {
            #pragma unroll
            for (int pr = 0; pr < 2; ++pr) {
                float s0 = 0.f, s1 = 0.f;
                #pragma unroll
                for (int jj = 0; jj < 6; ++jj) {
                    if (jj != 1) {  // B_TAB[1] == 0
                        const float bco = BTv[jj];
                        unsigned int p = kp[jj][nt * 2 + pr];
                        s0 += bco * frombits(p & 0xffffu);
                        s1 += bco * frombits(p >> 16);
                    }
                }
                z[nt][pr * 2 + 0] += dt * s0;
                z[nt][pr * 2 + 1] += dt * s1;
            }
        }
        #pragma unroll
        for (int rg = 0; rg < 4; ++rg)
            lp[rg] -= dt * (BTv[0] * klp[0][rg] + BTv[2] * klp[2][rg] + BTv[3] * klp[3][rg]
                          + BTv[4] * klp[4][rg] + BTv[5] * klp[5][rg]);
    }

    // ---------------- epilogue: z out, log_px = log_pz - dlogp ----------------
    float ss0 = 0.f, ss1 = 0.f, ss2 = 0.f, ss3 = 0.f;
    #pragma unroll
    for (int nt = 0; nt < 4; ++nt) {
        ss0 += z[nt][0] * z[nt][0];
        ss1 += z[nt][1] * z[nt][1];
        ss2 += z[nt][2] * z[nt][2];
        ss3 += z[nt][3] * z[nt][3];
        #pragma unroll
        for (int rg = 0; rg < 4; ++rg)
            Og[(row0 + rr + rg) * 64 + nt * 16 + l16] = z[nt][rg];
    }
    ss0 += __shfl_xor(ss0, 1); ss0 += __shfl_xor(ss0, 2);
    ss0 += __shfl_xor(ss0, 4); ss0 += __shfl_xor(ss0, 8);
    ss1 += __shfl_xor(ss1, 1); ss1 += __shfl_xor(ss1, 2);
    ss1 += __shfl_xor(ss1, 4); ss1 += __shfl_xor(ss1, 8);
    ss2 += __shfl_xor(ss2, 1); ss2 += __shfl_xor(ss2, 2);
    ss2 += __shfl_xor(ss2, 4); ss2 += __shfl_xor(ss2, 8);
    ss3 += __shfl_xor(ss3, 1); ss3 += __shfl_xor(ss3, 2);
    ss3 += __shfl_xor(ss3, 4); ss3 += __shfl_xor(ss3, 8);
    if (l16 == 0) {
        const float CLOG = -58.8120661f;  // -32*ln(2*pi)
        Og[32768 * 64 + row0 + rr + 0] = CLOG - 0.5f * ss0 - lp[0];
        Og[32768 * 64 + row0 + rr + 1] = CLOG - 0.5f * ss1 - lp[1];
        Og[32768 * 64 + row0 + rr + 2] = CLOG - 0.5f * ss2 - lp[2];
        Og[32768 * 64 + row0 + rr + 3] = CLOG - 0.5f * ss3 - lp[3];
    }
}

extern "C" void kernel_launch(void* const* d_in, const int* in_sizes, int n_in,
                              void* d_out, int out_size, void* d_ws, size_t ws_size,
                              hipStream_t stream) {
    const float* Yg  = (const float*)d_in[0];
    const float* Eg  = (const float*)d_in[1];
    const float* W1g = (const float*)d_in[2];  // [65][256]
    const float* b1g = (const float*)d_in[3];
    const float* W2g = (const float*)d_in[4];  // [256][64]
    const float* b2g = (const float*)d_in[5];
    float* Og = (float*)d_out;                 // z (32768*64) then log_px (32768)
    cnf_kernel<<<dim3(256), dim3(512), 0, stream>>>(Yg, Eg, W1g, b1g, W2g, b2g, Og);
}

// Round 2
// 1029.048 us; speedup vs baseline: 1.0567x; 1.0567x over previous
//
#include <hip/hip_runtime.h>

// CNF forward: 8 fixed dopri5 steps, 6 stages each, rows independent.
// One persistent kernel: 256 blocks x 512 threads; wave handles 16 rows.
// MFMA 16x16x32 bf16; weights in LDS; k's/state/ghv in registers (C-layout).
//
// R2: pin waves_per_eu to (2,2) -- LDS (113KB) already caps at 1 WG/CU, so the
// 256-VGPR budget is free; R1's compiler heuristic targeted 128 VGPRs and
// spilled ~2.9GB/launch to scratch. Also: klp[] removed (inline lp accum),
// b1/W1_t/b2 moved from LDS to registers.

typedef __bf16 bf16x8 __attribute__((ext_vector_type(8)));
typedef float  f32x4  __attribute__((ext_vector_type(4)));

#define MFMA16(a, b, c) __builtin_amdgcn_mfma_f32_16x16x32_bf16((a), (b), (c), 0, 0, 0)

__device__ __forceinline__ unsigned int bfbits(float x) {
    __bf16 b = (__bf16)x;                      // RNE fp32->bf16
    return (unsigned int)__builtin_bit_cast(unsigned short, b);
}
__device__ __forceinline__ float frombits(unsigned int u16) {
    return __builtin_bit_cast(float, u16 << 16);
}
__device__ __forceinline__ unsigned int pack2(float lo, float hi) {
    return bfbits(lo) | (bfbits(hi) << 16);
}
__device__ __forceinline__ float fast_tanh(float x) {
    // tanh(x) = 1 - 2/(exp(2x)+1); exp overflow/underflow saturate correctly.
    float e = __expf(2.0f * x);
    return 1.0f - 2.0f * __builtin_amdgcn_rcpf(e + 1.0f);
}

extern "C" __global__ __attribute__((amdgpu_waves_per_eu(2, 2))) void
__launch_bounds__(512)
cnf_kernel(const float* __restrict__ Yg, const float* __restrict__ Eg,
           const float* __restrict__ W1g, const float* __restrict__ b1g,
           const float* __restrict__ W2g, const float* __restrict__ b2g,
           float* __restrict__ Og)
{
    // ---- LDS (~111 KB; 1 WG/CU) ----
    __shared__ __align__(16) __bf16 sW1aT[256 * 72];   // [j][d] W1a^T, d-contig per j
    __shared__ __align__(16) __bf16 sW2U[256 * 72];    // phase1: W2 [j][d]; phase2: W2^T [d*264+j]
    __shared__ __align__(16) __bf16 sY[8][16 * 72];    // per-wave y stage buf [m][d]
    __shared__ __align__(16) __bf16 sH[8][16 * 40];    // per-wave h chunk [m][kloc 0..31]
    __shared__ __align__(16) float  sScr[8][16 * 17 + 4]; // per-wave transpose scratch

    const int tid  = threadIdx.x;
    const int wave = tid >> 6;
    const int lane = tid & 63;
    const int quad = lane >> 4;
    const int l16  = lane & 15;
    const int row0 = blockIdx.x * 128 + wave * 16;  // 16 rows per wave
    const int rr   = quad * 4;                      // C-layout row base (rows rr..rr+3)

    // ---------------- phase-1 weight staging ----------------
    for (int idx = tid; idx < 64 * 256; idx += 512) {         // W1a^T
        int d = idx >> 8, j = idx & 255;
        sW1aT[j * 72 + d] = (__bf16)W1g[idx];
    }
    for (int idx = tid; idx < 256 * 64; idx += 512) {         // W2 row-major
        int j = idx >> 6, d = idx & 63;
        sW2U[j * 72 + d] = (__bf16)W2g[idx];
    }
    __syncthreads();

    // bias / time-row / b2 in registers (same values across quads -> L2 broadcast)
    float b1v[16], w1tv[16];
    #pragma unroll
    for (int jt = 0; jt < 16; ++jt) {
        b1v[jt]  = b1g[jt * 16 + l16];
        w1tv[jt] = W1g[64 * 256 + jt * 16 + l16];
    }
    float bb[4];
    #pragma unroll
    for (int nt = 0; nt < 4; ++nt) bb[nt] = b2g[nt * 16 + l16];

    __bf16* yb  = sY[wave];
    __bf16* hb  = sH[wave];
    float*  scr = sScr[wave];

    // ---------------- stage e into ybuf (wave-local) ----------------
    #pragma unroll
    for (int nt = 0; nt < 4; ++nt)
        #pragma unroll
        for (int rg = 0; rg < 4; ++rg)
            yb[(rr + rg) * 72 + nt * 16 + l16] =
                (__bf16)Eg[(row0 + rr + rg) * 64 + nt * 16 + l16];

    // A-frags of e: A[m=l16][k=d], d-contig
    bf16x8 ae0 = *(const bf16x8*)(yb + l16 * 72 + quad * 8);
    bf16x8 ae1 = *(const bf16x8*)(yb + l16 * 72 + 32 + quad * 8);

    // ---------------- precompute ghv = (e@W1a) * (e@W2^T), C-layout regs ----------------
    unsigned int ghvp[32];  // [jt][pair], bf16x2
    #pragma unroll
    for (int tt = 0; tt < 16; ++tt) {
        f32x4 vacc = {0.f, 0.f, 0.f, 0.f};
        f32x4 gacc = {0.f, 0.f, 0.f, 0.f};
        // v tile: A=e, B=W1a (k=d contig via sW1aT)
        bf16x8 wb0 = *(const bf16x8*)(sW1aT + (tt * 16 + l16) * 72 + quad * 8);
        bf16x8 wb1 = *(const bf16x8*)(sW1aT + (tt * 16 + l16) * 72 + 32 + quad * 8);
        vacc = MFMA16(ae0, wb0, vacc);
        vacc = MFMA16(ae1, wb1, vacc);
        // gh0^T tile: A=W2 rows j (k=d contig), B=e^T (same frags as ae)
        bf16x8 aw0 = *(const bf16x8*)(sW2U + (tt * 16 + l16) * 72 + quad * 8);
        bf16x8 aw1 = *(const bf16x8*)(sW2U + (tt * 16 + l16) * 72 + 32 + quad * 8);
        gacc = MFMA16(aw0, ae0, gacc);
        gacc = MFMA16(aw1, ae1, gacc);
        // gacc lane holds gh0[j_local=rr+rg][r_hat=l16]; transpose via scratch
        #pragma unroll
        for (int rg = 0; rg < 4; ++rg) scr[(rr + rg) * 17 + l16] = gacc[rg];
        __syncthreads();
        float p0 = scr[l16 * 17 + rr + 0] * vacc[0];
        float p1 = scr[l16 * 17 + rr + 1] * vacc[1];
        float p2 = scr[l16 * 17 + rr + 2] * vacc[2];
        float p3 = scr[l16 * 17 + rr + 3] * vacc[3];
        ghvp[tt * 2 + 0] = pack2(p0, p1);
        ghvp[tt * 2 + 1] = pack2(p2, p3);
        __syncthreads();
    }

    // ---------------- load z state (fp32, C-layout regs) ----------------
    float z[4][4];  // [nt][reg]: (row=rr+reg, d=nt*16+l16)
    #pragma unroll
    for (int nt = 0; nt < 4; ++nt)
        #pragma unroll
        for (int rg = 0; rg < 4; ++rg)
            z[nt][rg] = Yg[(row0 + rr + rg) * 64 + nt * 16 + l16];

    // ---------------- phase-2: overwrite union region with W2^T ----------------
    __syncthreads();
    for (int idx = tid; idx < 256 * 64; idx += 512) {
        int j = idx >> 6, d = idx & 63;
        sW2U[d * 264 + j] = (__bf16)W2g[idx];  // [d][j], j-contig per d
    }
    __syncthreads();

    // ---------------- dopri5 main loop (no block syncs inside) ----------------
    constexpr float AT[6][5] = {
        {0.f, 0.f, 0.f, 0.f, 0.f},
        {0.2f, 0.f, 0.f, 0.f, 0.f},
        {3.f / 40.f, 9.f / 40.f, 0.f, 0.f, 0.f},
        {44.f / 45.f, -56.f / 15.f, 32.f / 9.f, 0.f, 0.f},
        {19372.f / 6561.f, -25360.f / 2187.f, 64448.f / 6561.f, -212.f / 729.f, 0.f},
        {9017.f / 3168.f, -355.f / 33.f, 46732.f / 5247.f, 49.f / 176.f, -5103.f / 18656.f},
    };
    constexpr float CTv[6] = {0.f, 0.2f, 0.3f, 0.8f, 8.f / 9.f, 1.f};
    constexpr float BTv[6] = {35.f / 384.f, 0.f, 500.f / 1113.f, 125.f / 192.f,
                              -2187.f / 6784.f, 11.f / 84.f};
    const float dt = 0.125f;

    unsigned int kp[6][8];   // k_dz bf16-packed, [stage][nt*2+pair]
    float lp[4] = {0.f, 0.f, 0.f, 0.f};

    for (int step = 0; step < 8; ++step) {
        const float t0 = dt * (float)step;
        #pragma unroll
        for (int st = 0; st < 6; ++st) {
            // ---- build stage state y = z + dt*sum(a_ij k_j) -> ybuf (bf16) ----
            #pragma unroll
            for (int nt = 0; nt < 4; ++nt) {
                #pragma unroll
                for (int pr = 0; pr < 2; ++pr) {
                    float a0 = 0.f, a1 = 0.f;
                    #pragma unroll
                    for (int jj = 0; jj < 5; ++jj) {
                        if (jj < st) {
                            const float aco = AT[st][jj];
                            unsigned int p = kp[jj][nt * 2 + pr];
                            a0 += aco * frombits(p & 0xffffu);
                            a1 += aco * frombits(p >> 16);
                        }
                    }
                    float y0 = z[nt][pr * 2 + 0] + dt * a0;
                    float y1 = z[nt][pr * 2 + 1] + dt * a1;
                    yb[(rr + pr * 2 + 0) * 72 + nt * 16 + l16] = (__bf16)y0;
                    yb[(rr + pr * 2 + 1) * 72 + nt * 16 + l16] = (__bf16)y1;
                }
            }
            const float ti = t0 + CTv[st] * dt;

            // ---- RHS eval ----
            bf16x8 a10 = *(const bf16x8*)(yb + l16 * 72 + quad * 8);
            bf16x8 a11 = *(const bf16x8*)(yb + l16 * 72 + 32 + quad * 8);
            f32x4 fa0 = {0.f, 0.f, 0.f, 0.f}, fa1 = {0.f, 0.f, 0.f, 0.f};
            f32x4 fa2 = {0.f, 0.f, 0.f, 0.f}, fa3 = {0.f, 0.f, 0.f, 0.f};
            float dv0 = 0.f, dv1 = 0.f, dv2 = 0.f, dv3 = 0.f;
            #pragma unroll
            for (int kk2 = 0; kk2 < 8; ++kk2) {
                #pragma unroll
                for (int hf = 0; hf < 2; ++hf) {
                    const int jt = kk2 * 2 + hf;
                    f32x4 ua = {0.f, 0.f, 0.f, 0.f};
                    bf16x8 wb0 = *(const bf16x8*)(sW1aT + (jt * 16 + l16) * 72 + quad * 8);
                    ua = MFMA16(a10, wb0, ua);
                    bf16x8 wb1 = *(const bf16x8*)(sW1aT + (jt * 16 + l16) * 72 + 32 + quad * 8);
                    ua = MFMA16(a11, wb1, ua);
                    const float bw = b1v[jt] + ti * w1tv[jt];
                    float h0 = fast_tanh(ua[0] + bw);
                    float h1 = fast_tanh(ua[1] + bw);
                    float h2 = fast_tanh(ua[2] + bw);
                    float h3 = fast_tanh(ua[3] + bw);
                    unsigned int gp0 = ghvp[jt * 2 + 0], gp1 = ghvp[jt * 2 + 1];
                    dv0 += frombits(gp0 & 0xffffu) * (1.f - h0 * h0);
                    dv1 += frombits(gp0 >> 16)     * (1.f - h1 * h1);
                    dv2 += frombits(gp1 & 0xffffu) * (1.f - h2 * h2);
                    dv3 += frombits(gp1 >> 16)     * (1.f - h3 * h3);
                    __bf16* hw = hb + hf * 16 + l16;
                    hw[(rr + 0) * 40] = (__bf16)h0;
                    hw[(rr + 1) * 40] = (__bf16)h1;
                    hw[(rr + 2) * 40] = (__bf16)h2;
                    hw[(rr + 3) * 40] = (__bf16)h3;
                }
                // matmul-2 K-chunk: f += h_chunk @ W2[kk2*32:+32, :]
                bf16x8 a2  = *(const bf16x8*)(hb + l16 * 40 + quad * 8);
                bf16x8 w20 = *(const bf16x8*)(sW2U + ( 0 + l16) * 264 + kk2 * 32 + quad * 8);
                fa0 = MFMA16(a2, w20, fa0);
                bf16x8 w21 = *(const bf16x8*)(sW2U + (16 + l16) * 264 + kk2 * 32 + quad * 8);
                fa1 = MFMA16(a2, w21, fa1);
                bf16x8 w22 = *(const bf16x8*)(sW2U + (32 + l16) * 264 + kk2 * 32 + quad * 8);
                fa2 = MFMA16(a2, w22, fa2);
                bf16x8 w23 = *(const bf16x8*)(sW2U + (48 + l16) * 264 + kk2 * 32 + quad * 8);
                fa3 = MFMA16(a2, w23, fa3);
            }
            // epilogue: + b2, pack k_dz
            kp[st][0] = pack2(fa0[0] + bb[0], fa0[1] + bb[0]);
            kp[st][1] = pack2(fa0[2] + bb[0], fa0[3] + bb[0]);
            kp[st][2] = pack2(fa1[0] + bb[1], fa1[1] + bb[1]);
            kp[st][3] = pack2(fa1[2] + bb[1], fa1[3] + bb[1]);
            kp[st][4] = pack2(fa2[0] + bb[2], fa2[1] + bb[2]);
            kp[st][5] = pack2(fa2[2] + bb[2], fa2[3] + bb[2]);
            kp[st][6] = pack2(fa3[0] + bb[3], fa3[1] + bb[3]);
            kp[st][7] = pack2(fa3[2] + bb[3], fa3[3] + bb[3]);
            // div reduction across the 16 j-lanes (same quad = same rows)
            dv0 += __shfl_xor(dv0, 1); dv0 += __shfl_xor(dv0, 2);
            dv0 += __shfl_xor(dv0, 4); dv0 += __shfl_xor(dv0, 8);
            dv1 += __shfl_xor(dv1, 1); dv1 += __shfl_xor(dv1, 2);
            dv1 += __shfl_xor(dv1, 4); dv1 += __shfl_xor(dv1, 8);
            dv2 += __shfl_xor(dv2, 1); dv2 += __shfl_xor(dv2, 2);
            dv2 += __shfl_xor(dv2, 4); dv2 += __shfl_xor(dv2, 8);
            dv3 += __shfl_xor(dv3, 1); dv3 += __shfl_xor(dv3, 2);
            dv3 += __shfl_xor(dv3, 4); dv3 += __shfl_xor(dv3, 8);
            // inline lp accumulation: lp = dlogp = -∫div
            const float dtB = dt * BTv[st];
            lp[0] -= dtB * dv0; lp[1] -= dtB * dv1;
            lp[2] -= dtB * dv2; lp[3] -= dtB * dv3;
        }

        // ---- combine: z += dt*sum(b_i k_i) ----
        #pragma unroll
        for (int nt = 0; nt < 4; ++nt) {
            #pragma unroll
            for (int pr = 0; pr < 2; ++pr) {
                float s0 = 0.f, s1 = 0.f;
                #pragma unroll
                for (int jj = 0; jj < 6; ++jj) {
                    if (jj != 1) {  // B_TAB[1] == 0
                        const float bco = BTv[jj];
                        unsigned int p = kp[jj][nt * 2 + pr];
                        s0 += bco * frombits(p & 0xffffu);
                        s1 += bco * frombits(p >> 16);
                    }
                }
                z[nt][pr * 2 + 0] += dt * s0;
                z[nt][pr * 2 + 1] += dt * s1;
            }
        }
    }

    // ---------------- epilogue: z out, log_px = log_pz - dlogp ----------------
    float ss0 = 0.f, ss1 = 0.f, ss2 = 0.f, ss3 = 0.f;
    #pragma unroll
    for (int nt = 0; nt < 4; ++nt) {
        ss0 += z[nt][0] * z[nt][0];
        ss1 += z[nt][1] * z[nt][1];
        ss2 += z[nt][2] * z[nt][2];
        ss3 += z[nt][3] * z[nt][3];
        #pragma unroll
        for (int rg = 0; rg < 4; ++rg)
            Og[(row0 + rr + rg) * 64 + nt * 16 + l16] = z[nt][rg];
    }
    ss0 += __shfl_xor(ss0, 1); ss0 += __shfl_xor(ss0, 2);
    ss0 += __shfl_xor(ss0, 4); ss0 += __shfl_xor(ss0, 8);
    ss1 += __shfl_xor(ss1, 1); ss1 += __shfl_xor(ss1, 2);
    ss1 += __shfl_xor(ss1, 4); ss1 += __shfl_xor(ss1, 8);
    ss2 += __shfl_xor(ss2, 1); ss2 += __shfl_xor(ss2, 2);
    ss2 += __shfl_xor(ss2, 4); ss2 += __shfl_xor(ss2, 8);
    ss3 += __shfl_xor(ss3, 1); ss3 += __shfl_xor(ss3, 2);
    ss3 += __shfl_xor(ss3, 4); ss3 += __shfl_xor(ss3, 8);
    if (l16 == 0) {
        const float CLOG = -58.8120661f;  // -32*ln(2*pi)
        Og[32768 * 64 + row0 + rr + 0] = CLOG - 0.5f * ss0 - lp[0];
        Og[32768 * 64 + row0 + rr + 1] = CLOG - 0.5f * ss1 - lp[1];
        Og[32768 * 64 + row0 + rr + 2] = CLOG - 0.5f * ss2 - lp[2];
        Og[32768 * 64 + row0 + rr + 3] = CLOG - 0.5f * ss3 - lp[3];
    }
}

extern "C" void kernel_launch(void* const* d_in, const int* in_sizes, int n_in,
                              void* d_out, int out_size, void* d_ws, size_t ws_size,
                              hipStream_t stream) {
    const float* Yg  = (const float*)d_in[0];
    const float* Eg  = (const float*)d_in[1];
    const float* W1g = (const float*)d_in[2];  // [65][256]
    const float* b1g = (const float*)d_in[3];
    const float* W2g = (const float*)d_in[4];  // [256][64]
    const float* b2g = (const float*)d_in[5];
    float* Og = (float*)d_out;                 // z (32768*64) then log_px (32768)
    cnf_kernel<<<dim3(256), dim3(512), 0, stream>>>(Yg, Eg, W1g, b1g, W2g, b2g, Og);
}